// Round 3
// baseline (184.529 us; speedup 1.0000x reference)
//
#include <hip/hip_runtime.h>

// out[b,i,j] = sum_ch x[b,i,j,ch] * sign(w[((i-ch) mod 32)*32 + (j mod 32)])
// B=256, P=64, C=31. Fwd/bwd per-channel rolls cancel on the x index; only the
// mask row keeps (i-ch). Memory-bound: 130 MB read + 4 MB write -> ~21 us floor.
//
// Structure (round 3): barrier-free per-wave pipeline. Each wave owns 4 rows
// and a private 7936 B LDS region; global_load_lds prefetch of row k+1 is
// issued after row k's values are pulled into registers. No __syncthreads in
// the hot loop -> waves stay decoupled, no block-wide vmcnt(0) drain phasing.

#define CH 31
#define ROW_F4 496                 // 1984 floats per row / 4
#define WAVES_PER_BLOCK 4
#define ROWS_PER_WAVE 4
#define NBLOCKS 1024               // 1024*4 waves * 4 rows = 16384 rows total

typedef const __attribute__((address_space(1))) void* gptr_t;
typedef __attribute__((address_space(3))) void* lptr_t;

__device__ __forceinline__ void stage_row(const float4* __restrict__ src,
                                          float4* dst, int lane)
{
#pragma unroll
    for (int it = 0; it < 7; ++it) {
        __builtin_amdgcn_global_load_lds((gptr_t)(src + it * 64 + lane),
                                         (lptr_t)(dst + it * 64 + lane), 16, 0, 0);
    }
    if (lane < ROW_F4 - 7 * 64) {   // last 48 float4
        __builtin_amdgcn_global_load_lds((gptr_t)(src + 448 + lane),
                                         (lptr_t)(dst + 448 + lane), 16, 0, 0);
    }
}

__global__ __launch_bounds__(256) void codednet_kernel(
    const float* __restrict__ x,
    const float* __restrict__ w,
    float* __restrict__ out)
{
    __shared__ float4 xs4[WAVES_PER_BLOCK][ROW_F4];  // 31744 B, one row per wave
    __shared__ float  s_lut[1024];                   //  4096 B sign LUT

    const int t    = threadIdx.x;
    const int lane = t & 63;
    const int wl   = t >> 6;                                   // wave in block
    const int wid  = blockIdx.x * WAVES_PER_BLOCK + wl;        // global wave
    const int row0 = wid * ROWS_PER_WAVE;

    // ---- issue row0 staging first so it overlaps LUT init ----
    stage_row((const float4*)x + (size_t)row0 * ROW_F4, &xs4[wl][0], lane);

    // ---- sign LUT: 1024 w values, 4/thread ----
    {
        float4 wv = ((const float4*)w)[t];
        float4 sv;
        sv.x = (wv.x > 0.f) ? 1.f : ((wv.x < 0.f) ? -1.f : 0.f);
        sv.y = (wv.y > 0.f) ? 1.f : ((wv.y < 0.f) ? -1.f : 0.f);
        sv.z = (wv.z > 0.f) ? 1.f : ((wv.z < 0.f) ? -1.f : 0.f);
        sv.w = (wv.w > 0.f) ? 1.f : ((wv.w < 0.f) ? -1.f : 0.f);
        ((float4*)s_lut)[t] = sv;
    }
    __syncthreads();   // one-time: LUT visible to all; also drains row0 DMA

    const int j  = lane;
    const int jm = j & 31;
    const float* __restrict__ xbase = (const float*)&xs4[wl][0] + j * CH;

#pragma unroll 1
    for (int k = 0; k < ROWS_PER_WAVE; ++k) {
        const int row = row0 + k;

        // row k's DMA must have landed (covers k>0; k=0 drained by barrier)
        asm volatile("s_waitcnt vmcnt(0)" ::: "memory");

        // pull this thread's 31 x-values into registers
        float xv[CH];
#pragma unroll
        for (int c = 0; c < CH; ++c) xv[c] = xbase[c];
        asm volatile("s_waitcnt lgkmcnt(0)" ::: "memory");  // reads landed in regs

        // prefetch row k+1 into the same per-wave buffer (WAR-safe: regs hold k)
        if (k + 1 < ROWS_PER_WAVE) {
            stage_row((const float4*)x + (size_t)(row + 1) * ROW_F4, &xs4[wl][0], lane);
        }

        const int i = row & 63;
        float a0 = 0.f, a1 = 0.f, a2 = 0.f, a3 = 0.f;
#pragma unroll
        for (int c = 0; c < 28; c += 4) {
            a0 += xv[c + 0] * s_lut[(((i - c - 0) & 31) << 5) | jm];
            a1 += xv[c + 1] * s_lut[(((i - c - 1) & 31) << 5) | jm];
            a2 += xv[c + 2] * s_lut[(((i - c - 2) & 31) << 5) | jm];
            a3 += xv[c + 3] * s_lut[(((i - c - 3) & 31) << 5) | jm];
        }
        a0 += xv[28] * s_lut[(((i - 28) & 31) << 5) | jm];
        a1 += xv[29] * s_lut[(((i - 29) & 31) << 5) | jm];
        a2 += xv[30] * s_lut[(((i - 30) & 31) << 5) | jm];

        const float sum = (a0 + a1) + (a2 + a3);
        __builtin_nontemporal_store(sum, &out[(size_t)row * 64 + j]);
    }
}

extern "C" void kernel_launch(void* const* d_in, const int* in_sizes, int n_in,
                              void* d_out, int out_size, void* d_ws, size_t ws_size,
                              hipStream_t stream) {
    const float* x = (const float*)d_in[0];   // [256,64,64,31] f32
    const float* w = (const float*)d_in[1];   // [1024] f32
    float* out = (float*)d_out;               // [256,64,64] f32

    codednet_kernel<<<NBLOCKS, 256, 0, stream>>>(x, w, out);
}